// Round 8
// baseline (278.185 us; speedup 1.0000x reference)
//
#include <hip/hip_runtime.h>
#include <math.h>

#define CC 64
#define CQv 8
#define CRv 4
#define BB 4
#define RR 224
#define TT 224
#define NN (RR*TT)   // 50176
#define LOG2E 1.4426950408889634f

typedef __attribute__((ext_vector_type(8))) short short8;
typedef __attribute__((ext_vector_type(4))) float f32x4;

__device__ __forceinline__ f32x4 mfma_bf16(short8 a, short8 b, f32x4 c){
    return __builtin_amdgcn_mfma_f32_16x16x32_bf16(a, b, c, 0, 0, 0);
}

__device__ __forceinline__ ushort f2bf(float f){
    union { float f; unsigned u; } v; v.f = f;
    unsigned r = v.u + 0x7fffu + ((v.u >> 16) & 1u);
    return (ushort)(r >> 16);
}
__device__ __forceinline__ float bf2f(ushort u){
    return __uint_as_float((unsigned)u << 16);
}
// pack two f32 as truncated bf16 pair: [lo=a, hi=b]
__device__ __forceinline__ unsigned packbf(float a, float b){
    return __builtin_amdgcn_perm(__float_as_uint(b), __float_as_uint(a), 0x07060302u);
}
// balanced XOR swizzle: 512B rows (32 slots of 16B)
__device__ __forceinline__ int vswz(int row, int uslot){
    return (uslot ^ (row & 7) ^ ((row >> 3) & 7)) << 4;
}

// ---------------- K1: q,k,v 1x1 convs via MFMA + per-block mean partials ----------------
// qB[b][pos][8], kB[b][pos][8] (k pre-scaled by log2e), vB[b][pos][64]  (bf16)
__global__ __launch_bounds__(256) void k_qkv(
    const float* __restrict__ x,
    const float* __restrict__ Wq, const float* __restrict__ bq,
    const float* __restrict__ Wk, const float* __restrict__ bk,
    const float* __restrict__ Wv, const float* __restrict__ bv,
    ushort* __restrict__ qB, ushort* __restrict__ kB, ushort* __restrict__ vB,
    float* __restrict__ partial)
{
    const int tid = threadIdx.x;
    const int w = tid >> 6, l = tid & 63, l15 = l & 15, lg = l >> 4;
    const int blk = blockIdx.x;
    const int b = blk / 196, pb = blk - b*196;
    const int n0 = pb*256;
    const float* xb = x + (size_t)b*CC*NN;

    short8 afr[5][2];
#pragma unroll
    for (int ot = 0; ot < 5; ++ot) {
        int oo = ot*16 + l15;
        const float* wr = (oo < 8) ? (Wq + oo*64)
                        : (oo < 16) ? (Wk + (oo-8)*64)
                                    : (Wv + (oo-16)*64);
        float scl = (oo >= 8 && oo < 16) ? LOG2E : 1.0f;
#pragma unroll
        for (int ks = 0; ks < 2; ++ks) {
            const float* p = wr + ks*32 + lg*8;
            float4 w0 = *(const float4*)p, w1 = *(const float4*)(p+4);
            short8 f;
            f[0]=f2bf(w0.x*scl); f[1]=f2bf(w0.y*scl); f[2]=f2bf(w0.z*scl); f[3]=f2bf(w0.w*scl);
            f[4]=f2bf(w1.x*scl); f[5]=f2bf(w1.y*scl); f[6]=f2bf(w1.z*scl); f[7]=f2bf(w1.w*scl);
            afr[ot][ks] = f;
        }
    }
    f32x4 binit[5];
#pragma unroll
    for (int ot = 0; ot < 5; ++ot) {
        const float* bp;
        float scl = 1.0f;
        if (ot == 0) { bp = (lg < 2) ? (bq + lg*4) : (bk + (lg-2)*4); if (lg >= 2) scl = LOG2E; }
        else           bp = bv + (ot-1)*16 + lg*4;
        float4 bb4 = *(const float4*)bp;
        binit[ot] = (f32x4){bb4.x*scl, bb4.y*scl, bb4.z*scl, bb4.w*scl};
    }

    float msum[16];
#pragma unroll
    for (int i = 0; i < 16; ++i) msum[i] = 0.f;

#pragma unroll
    for (int j = 0; j < 4; ++j) {
        int n = n0 + (w*4 + j)*16 + l15;
        short8 bfr[2];
#pragma unroll
        for (int ks = 0; ks < 2; ++ks) {
            const float* xp = xb + (size_t)(ks*32 + lg*8)*NN + n;
            short8 f;
#pragma unroll
            for (int e = 0; e < 8; ++e) {
                float xv = xp[(size_t)e*NN];
                f[e] = f2bf(xv);
                msum[ks*8 + e] += xv;
            }
            bfr[ks] = f;
        }
#pragma unroll
        for (int ot = 0; ot < 5; ++ot) {
            f32x4 acc = binit[ot];
            acc = mfma_bf16(afr[ot][0], bfr[0], acc);
            acc = mfma_bf16(afr[ot][1], bfr[1], acc);
            ushort4 pk;
            pk.x = f2bf(acc[0]); pk.y = f2bf(acc[1]);
            pk.z = f2bf(acc[2]); pk.w = f2bf(acc[3]);
            if (ot == 0) {
                ushort* dst = (lg < 2) ? (qB + ((size_t)b*NN + n)*8 + lg*4)
                                       : (kB + ((size_t)b*NN + n)*8 + (lg-2)*4);
                *(ushort4*)dst = pk;
            } else {
                int oc = (ot-1)*16 + lg*4;
                *(ushort4*)(vB + ((size_t)b*NN + n)*64 + oc) = pk;
            }
        }
    }

#pragma unroll
    for (int i = 0; i < 16; ++i) {
        float s = msum[i];
        s += __shfl_xor(s, 1); s += __shfl_xor(s, 2);
        s += __shfl_xor(s, 4); s += __shfl_xor(s, 8);
        msum[i] = s;
    }
    __shared__ float msums[4][4][16];
    if (l15 == 0) {
#pragma unroll
        for (int i = 0; i < 16; ++i) msums[w][lg][i] = msum[i];
    }
    __syncthreads();
    if (tid < 64) {
        int c = tid;
        int lgi = (c >> 3) & 3, ii = (c >> 5)*8 + (c & 7);
        float t = msums[0][lgi][ii] + msums[1][lgi][ii] + msums[2][lgi][ii] + msums[3][lgi][ii];
        partial[(size_t)blk*64 + c] = t;
    }
}

// ---------------- transpose q/k: [224][224] of 16B units per b (both in one) ----------------
__global__ __launch_bounds__(256) void k_tq(const uint4* __restrict__ qs, const uint4* __restrict__ ks,
                                            uint4* __restrict__ qd, uint4* __restrict__ kd)
{
    __shared__ uint4 tile[32][33];
    int z = blockIdx.z;
    int b = z & 3;
    const uint4* sp = ((z >= 4) ? ks : qs) + (size_t)b*NN;
    uint4*       dp = ((z >= 4) ? kd : qd) + (size_t)b*NN;
    int t0 = blockIdx.x*32, r0 = blockIdx.y*32;
    int tx = threadIdx.x & 31, ty = threadIdx.x >> 5;
#pragma unroll
    for (int j = 0; j < 4; ++j) { int lr = ty + 8*j; tile[lr][tx] = sp[(size_t)(r0+lr)*224 + t0 + tx]; }
    __syncthreads();
#pragma unroll
    for (int j = 0; j < 4; ++j) { int lt = ty + 8*j; dp[(size_t)(t0+lt)*224 + r0 + tx] = tile[tx][lt]; }
}

// ---------------- PV via MFMA: wave-independent chunks, in-wave att regroup ----------------
// Each wave owns 16-row chunks ch = w, w+4, ... (14 chunks of 16 rows).
// Score MFMA leaves att in the right lanes (l15 = r); regroup u-quads->u-octets via
// 2 cndmask + 4 ds_bpermute. PV computed transposed: acc = mfma(att, V) so each lane
// stores one aligned ushort4 per c-tile. One barrier total (after staging).
__global__ __launch_bounds__(256, 4) void k_pv(const ushort* __restrict__ qA, const ushort* __restrict__ kA,
                                               const ushort* __restrict__ qB, const ushort* __restrict__ kB,
                                               const ushort* __restrict__ vB,
                                               ushort* __restrict__ outA, ushort* __restrict__ outB,
                                               float* __restrict__ ZHt, float* __restrict__ ZWt)
{
    __shared__ __align__(16) ushort Vt[64*256];  // bf16 [c][u], XOR-swizzled 512B rows (32 KB)
    __shared__ __align__(16) ushort Kh[224*8];   // bf16 K rows (3.5 KB)

    const int tid = threadIdx.x;
    const int bid = blockIdx.x;
    const bool HM = bid < BB*224;
    const int blk = HM ? bid : bid - BB*224;
    const int b = blk / 224, o = blk - b*224;
    const ushort* Qsrc = (HM ? qA : qB) + (size_t)blk*1792;
    const ushort* Ksrc = (HM ? kA : kB) + (size_t)blk*1792;
    ushort* op = (HM ? outA : outB) + (size_t)blk*14336;
    float*  Zt = (HM ? ZHt : ZWt) + (size_t)blk*224;

    // ---- stage V^T: 4u x 8c register block -> 8x ds_write_b64 (balanced banks)
    {
        const uint4* vbase = (const uint4*)vB;
        for (int gi = tid; gi < 448; gi += 256) {
            int ublk = gi >> 3, sub = gi & 7;
            int u0 = ublk << 2;
            size_t base, stride;
            if (HM) { base = ((size_t)b*NN + (size_t)u0*224 + o)*8 + sub; stride = 1792; }
            else    { base = ((size_t)blk*224 + u0)*8 + sub;              stride = 8;    }
            uint4 r0 = vbase[base], r1 = vbase[base+stride], r2 = vbase[base+2*stride], r3 = vbase[base+3*stride];
            const ushort* p0 = (const ushort*)&r0;
            const ushort* p1 = (const ushort*)&r1;
            const ushort* p2 = (const ushort*)&r2;
            const ushort* p3 = (const ushort*)&r3;
            int half = (ublk & 1) * 8;
#pragma unroll
            for (int j = 0; j < 8; ++j) {
                int c = sub*8 + j;
                ushort4 col; col.x = p0[j]; col.y = p1[j]; col.z = p2[j]; col.w = p3[j];
                *(ushort4*)((char*)Vt + c*512 + vswz(c, ublk >> 1) + half) = col;
            }
        }
    }
    if (tid < 224) ((uint4*)Kh)[tid] = ((const uint4*)Ksrc)[tid];
    __syncthreads();

    const int w = tid >> 6, l = tid & 63;
    const int l15 = l & 15, lg = l >> 4;
    const short8 zfr = {0,0,0,0,0,0,0,0};
    const f32x4 zacc = {0.f,0.f,0.f,0.f};

    // bpermute source lanes (byte indices): regroup u-quads (per lg) -> u-octets
    const int src0 = (l15 + ((lg & 1) << 5)) << 2;   // lane l15 + 32*(lg&1)
    const int src1 = src0 + 64;                      // +16 lanes
    const bool hi = (lg >= 2);

    for (int ch = w; ch < 14; ch += 4) {
        short8 qf = zfr;
        if (lg == 0) qf = *(const short8*)(Qsrc + (size_t)(ch*16 + l15)*8);
        f32x4 acc0 = zacc, acc1 = zacc, acc2 = zacc, acc3 = zacc;
        float zsum = 0.f;
#pragma unroll
        for (int ks = 0; ks < 7; ++ks) {
            // score MFMAs for u-tiles 2ks, 2ks+1 (K broadcast; lg!=0 garbage ok, q is 0 there)
            short8 kf0 = *(const short8*)(Kh + (size_t)(ks*32 + l15)*8);
            short8 kf1 = *(const short8*)(Kh + (size_t)(ks*32 + 16 + l15)*8);
            f32x4 e0 = mfma_bf16(kf0, qf, zacc);
            f32x4 e1 = mfma_bf16(kf1, qf, zacc);
            float a0[4], a1[4];
#pragma unroll
            for (int g = 0; g < 4; ++g) {
                a0[g] = __builtin_amdgcn_exp2f(e0[g]);
                a1[g] = __builtin_amdgcn_exp2f(e1[g]);
            }
            if (HM && (ch >> 1) == ks) {     // diag tile: u == r
                if ((ch & 1) == 0) {
#pragma unroll
                    for (int g = 0; g < 4; ++g) if (lg*4 + g == l15) a0[g] = 0.f;
                } else {
#pragma unroll
                    for (int g = 0; g < 4; ++g) if (lg*4 + g == l15) a1[g] = 0.f;
                }
            }
            zsum += ((a0[0]+a0[1]) + (a0[2]+a0[3])) + ((a1[0]+a1[1]) + (a1[2]+a1[3]));
            unsigned p00 = packbf(a0[0], a0[1]), p01 = packbf(a0[2], a0[3]);
            unsigned p10 = packbf(a1[0], a1[1]), p11 = packbf(a1[2], a1[3]);
            unsigned s0 = hi ? p10 : p00;
            unsigned s1 = hi ? p11 : p01;
            int fx = __builtin_amdgcn_ds_bpermute(src0, (int)s0);
            int fy = __builtin_amdgcn_ds_bpermute(src0, (int)s1);
            int fz = __builtin_amdgcn_ds_bpermute(src1, (int)s0);
            int fw = __builtin_amdgcn_ds_bpermute(src1, (int)s1);
            int4 fi; fi.x = fx; fi.y = fy; fi.z = fz; fi.w = fw;
            short8 af = *(short8*)&fi;
            // PV (transposed): acc[r_local, c] += att x V
            {
                short8 vf0 = *(const short8*)((const char*)Vt + (size_t)(l15)*512       + vswz(l15,      ks*4 + lg));
                short8 vf1 = *(const short8*)((const char*)Vt + (size_t)(16 + l15)*512  + vswz(16 + l15, ks*4 + lg));
                short8 vf2 = *(const short8*)((const char*)Vt + (size_t)(32 + l15)*512  + vswz(32 + l15, ks*4 + lg));
                short8 vf3 = *(const short8*)((const char*)Vt + (size_t)(48 + l15)*512  + vswz(48 + l15, ks*4 + lg));
                acc0 = mfma_bf16(af, vf0, acc0);
                acc1 = mfma_bf16(af, vf1, acc1);
                acc2 = mfma_bf16(af, vf2, acc2);
                acc3 = mfma_bf16(af, vf3, acc3);
            }
        }
        // z row-sum: reduce across lg groups; lanes lg==0 hold rows ch*16+l15
        zsum += __shfl_xor(zsum, 16);
        zsum += __shfl_xor(zsum, 32);
        if (lg == 0) Zt[ch*16 + l15] = zsum;
        // store out^T: lane (l15=c_local, lg) holds 4 consecutive r
        {
            int rbase = ch*16 + lg*4;
            f32x4 av[4] = {acc0, acc1, acc2, acc3};
#pragma unroll
            for (int ct = 0; ct < 4; ++ct) {
                ushort4 pk;
                pk.x = f2bf(av[ct][0]); pk.y = f2bf(av[ct][1]);
                pk.z = f2bf(av[ct][2]); pk.w = f2bf(av[ct][3]);
                *(ushort4*)(op + (size_t)(ct*16 + l15)*224 + rbase) = pk;
            }
        }
    }
}

// ---------------- aux: Zi = g*rcp(ZH^T + ZW) tiles (blocks 0..195) + SE (block 196) ----------------
__global__ __launch_bounds__(256) void k_aux(const float* __restrict__ ZHt, const float* __restrict__ ZWt,
                                             const float* __restrict__ gammap,
                                             const float* __restrict__ partial,
                                             const float* __restrict__ W1, const float* __restrict__ W2,
                                             float* __restrict__ Zi, float* __restrict__ y2)
{
    const int blk = blockIdx.x;
    if (blk < 196) {
        __shared__ float tile[32][33];
        int b = blk / 49, rem = blk - b*49;
        int t0 = (rem % 7)*32, v0 = (rem / 7)*32;
        int tx = threadIdx.x & 31, ty = threadIdx.x >> 5;
        float g = gammap[0];
#pragma unroll
        for (int j = 0; j < 4; ++j) {
            int tl = ty + 8*j;
            tile[tl][tx] = ZHt[((size_t)(b*224 + t0 + tl))*224 + v0 + tx];
        }
        __syncthreads();
#pragma unroll
        for (int j = 0; j < 4; ++j) {
            int vl = ty + 8*j;
            size_t i = ((size_t)(b*224 + v0 + vl))*224 + t0 + tx;
            float zs = tile[tx][vl] + ZWt[i];
            Zi[i] = g * __builtin_amdgcn_rcpf(zs);
        }
    } else {
        __shared__ float mean_s[4][64];
        int tid = threadIdx.x;
        int b = tid >> 6, c = tid & 63;
        float s = 0.f;
        for (int i = 0; i < 196; ++i) s += partial[((size_t)(b*196 + i))*64 + c];
        mean_s[b][c] = s * (1.0f/NN);
        __syncthreads();
        float h[CRv];
#pragma unroll
        for (int j = 0; j < CRv; ++j) {
            float t = 0.f;
#pragma unroll
            for (int cc = 0; cc < CC; ++cc) t += W1[j*CC + cc] * mean_s[b][cc];
            h[j] = fmaxf(t, 0.f);
        }
        float s2 = 0.f;
#pragma unroll
        for (int j = 0; j < CRv; ++j) s2 += W2[c*CRv + j] * h[j];
        y2[tid] = 1.f/(1.f + __expf(-s2));
    }
}

// ---------------- final: out = x*(1+y2) + (outA^T + outB)*Zi ----------------
__global__ __launch_bounds__(256) void k_final(const float* __restrict__ x,
                                               const ushort* __restrict__ outA,
                                               const ushort* __restrict__ outB,
                                               const float* __restrict__ Zi,
                                               const float* __restrict__ y2,
                                               float* __restrict__ out)
{
    __shared__ ushort tile[32][34];
    int bc = blockIdx.z;
    int b = bc >> 6, c = bc & 63;
    int t0 = blockIdx.x*32, r0 = blockIdx.y*32;
    int tx = threadIdx.x & 31, ty = threadIdx.x >> 5;
    float scale = 1.f + y2[bc];
#pragma unroll
    for (int j = 0; j < 4; ++j) {
        int tl = ty + 8*j;
        tile[tl][tx] = outA[((size_t)(b*224 + t0 + tl)*64 + c)*224 + r0 + tx];
    }
    __syncthreads();
#pragma unroll
    for (int j = 0; j < 4; ++j) {
        int rl = ty + 8*j;
        size_t pidx = (size_t)(r0 + rl)*224 + t0 + tx;
        size_t idx = (size_t)bc*NN + pidx;
        float a = bf2f(tile[tx][rl]);
        float wv = bf2f(outB[((size_t)(b*224 + r0 + rl)*64 + c)*224 + t0 + tx]);
        float zi = Zi[(size_t)b*NN + pidx];
        out[idx] = x[idx]*scale + (a + wv)*zi;
    }
}

// ---------------- launcher ----------------
extern "C" void kernel_launch(void* const* d_in, const int* in_sizes, int n_in,
                              void* d_out, int out_size, void* d_ws, size_t ws_size,
                              hipStream_t stream)
{
    const float* x  = (const float*)d_in[0];
    const float* Wq = (const float*)d_in[1];
    const float* bq = (const float*)d_in[2];
    const float* Wk = (const float*)d_in[3];
    const float* bk = (const float*)d_in[4];
    const float* Wv = (const float*)d_in[5];
    const float* bv = (const float*)d_in[6];
    const float* gm = (const float*)d_in[7];
    const float* W1 = (const float*)d_in[8];
    const float* W2 = (const float*)d_in[9];
    float* out = (float*)d_out;

    constexpr size_t QSZ = (size_t)BB*NN*CQv;
    constexpr size_t VSZ = (size_t)BB*NN*CC;
    constexpr size_t SSZ = (size_t)BB*NN;

    ushort* qB = (ushort*)d_ws;
    ushort* kB = qB + QSZ;
    ushort* vB = kB + QSZ;
    ushort* qA = vB + VSZ;
    ushort* kA = qA + QSZ;
    ushort* outA = kA + QSZ;
    ushort* outB = outA + VSZ;
    float*  ZHt = (float*)(outB + VSZ);
    float*  ZWt = ZHt + SSZ;
    float*  Zi  = ZWt + SSZ;
    float*  partial = Zi + SSZ;        // BB*196*64 = 50176 floats
    float*  y2 = partial + (size_t)BB*196*64;
    (void)ws_size; (void)in_sizes; (void)n_in; (void)out_size;

    k_qkv<<<BB*196, 256, 0, stream>>>(x, Wq, bq, Wk, bk, Wv, bv, qB, kB, vB, partial);
    k_tq<<<dim3(7,7,8), 256, 0, stream>>>((const uint4*)qB, (const uint4*)kB, (uint4*)qA, (uint4*)kA);

    k_pv<<<2*BB*224, 256, 0, stream>>>(qA, kA, qB, kB, vB, outA, outB, ZHt, ZWt);
    k_aux<<<197, 256, 0, stream>>>(ZHt, ZWt, gm, partial, W1, W2, Zi, y2);

    k_final<<<dim3(7,7,BB*CC), 256, 0, stream>>>(x, outA, outB, Zi, y2, out);
}